// Round 11
// baseline (93.891 us; speedup 1.0000x reference)
//
#include <hip/hip_runtime.h>
#include <math.h>

typedef __bf16 bf16x8 __attribute__((ext_vector_type(8)));
typedef float f32x4 __attribute__((ext_vector_type(4)));
typedef unsigned short u16;
typedef unsigned short u16x8 __attribute__((ext_vector_type(8)));
typedef unsigned int u32;

constexpr int BATCH = 2048;
constexpr int ROWS  = 4096;   // 2 steps x 2048
constexpr int HID   = 512;
constexpr int NACT  = 8;

__device__ __forceinline__ float gelu_f(float x) {
    return 0.5f * x * (1.0f + erff(x * 0.70710678118654752f));
}
__device__ __forceinline__ u16 f2bf(float f) {
    u32 u = __float_as_uint(f);
    return (u16)((u + 0x7FFFu + ((u >> 16) & 1u)) >> 16);
}
__device__ __forceinline__ float bf2f(u16 h) {
    return __uint_as_float(((u32)h) << 16);
}

// Fragment-chunk layout for every bf16 plane:
//   plane[(r>>4)*16 + (k>>5)][512], idx = (((k&31)>>3)*16 + (r&15))*8 + (k&7)
// A 16-row x 32-k tile is one contiguous 1KB block in exact MFMA-fragment
// lane order -> staging loads are single contiguous 1KB bursts.
__device__ __forceinline__ size_t fragoff(int r, int k) {
    return (size_t)(((r >> 4) * 16 + (k >> 5)) * 512
                    + (((k & 31) >> 3) * 16 + (r & 15)) * 8 + (k & 7));
}

// ---------------------------------------------------------------------------
// K_prep: z<4 -> transpose + hi/lo-split weight layer z into wt (frag layout)
//         z==4 (x<4,y==0) -> partials[x] = temb-slice @ W_in slice (no
//         cross-block reduction: summed by consumers; deterministic).
// ---------------------------------------------------------------------------
__global__ __launch_bounds__(256) void k_prep(
        const float* __restrict__ W1, const float* __restrict__ W2,
        const float* __restrict__ W3, const float* __restrict__ W4,
        const float* __restrict__ W_in,
        u16* __restrict__ wt, float* __restrict__ partials) {
    int z = blockIdx.z;
    if (z == 4) {
        if (blockIdx.x >= 4 || blockIdx.y != 0) return;
        __shared__ float temb[128];
        int x = blockIdx.x, t = threadIdx.x;
        if (t < 128) {
            int k = x * 128 + t;
            int p = k >> 1;
            float div = expf((float)(2 * p) * (-9.210340371976184f / 512.0f));
            temb[t] = (k & 1) ? cosf(49.0f * div) : sinf(49.0f * div);
        }
        __syncthreads();
#pragma unroll
        for (int half = 0; half < 2; ++half) {
            int col = half * 256 + t;
            float acc = 0.f;
            for (int kk = 0; kk < 128; ++kk)
                acc += temb[kk] * W_in[(size_t)(14 + x * 128 + kk) * HID + col];
            partials[x * HID + col] = acc;
        }
        return;
    }
    __shared__ float tile[32][33];
    const float* Ws[4] = {W1, W2, W3, W4};
    const float* W = Ws[z];
    u16* wh = wt + (size_t)z * 524288;
    u16* wl = wh + 262144;
    int kt = blockIdx.x * 32, nt = blockIdx.y * 32, t = threadIdx.x;
    int c = t & 31, r = t >> 5;
#pragma unroll
    for (int p = 0; p < 4; ++p)
        tile[r + p * 8][c] = W[(size_t)(kt + r + p * 8) * HID + nt + c];
    __syncthreads();
#pragma unroll
    for (int p = 0; p < 4; ++p) {
        int nl = r + p * 8, kl = c;
        float v = tile[kl][nl];
        u16 h = f2bf(v);
        u16 l2 = f2bf(v - bf2f(h));
        size_t o = fragoff(nt + nl, kt + kl);
        wh[o] = h;
        wl[o] = l2;
    }
}

// ---------------------------------------------------------------------------
// K_layer_in: input layer, each element computed once. One wave per row;
// lane o computes col-octet o: float4 weight loads, u16x8 frag stores.
// ---------------------------------------------------------------------------
__global__ __launch_bounds__(256) void k_layer_in(
        const float* __restrict__ x_pre, const float* __restrict__ noise,
        const float* __restrict__ W_in, const float* __restrict__ b_in,
        const float* __restrict__ partials,
        u16* __restrict__ Yh, u16* __restrict__ Yl) {
    int id = blockIdx.x * 256 + threadIdx.x;
    int r = id >> 6, oct = id & 63;
    int s = r >> 11, bidx = r & 2047;
    float xv[6], nz[8];
#pragma unroll
    for (int j = 0; j < 6; ++j) xv[j] = x_pre[bidx * 6 + j];
#pragma unroll
    for (int j = 0; j < 8; ++j) nz[j] = noise[(s * BATCH + bidx) * NACT + j];
    int nc = oct * 8;
    float acc[8];
#pragma unroll
    for (int q = 0; q < 2; ++q) {
        float4 bv = *(const float4*)&b_in[nc + q * 4];
        float4 p0 = *(const float4*)&partials[nc + q * 4];
        float4 p1 = *(const float4*)&partials[512 + nc + q * 4];
        float4 p2 = *(const float4*)&partials[1024 + nc + q * 4];
        float4 p3 = *(const float4*)&partials[1536 + nc + q * 4];
        acc[q * 4 + 0] = bv.x + p0.x + p1.x + p2.x + p3.x;
        acc[q * 4 + 1] = bv.y + p0.y + p1.y + p2.y + p3.y;
        acc[q * 4 + 2] = bv.z + p0.z + p1.z + p2.z + p3.z;
        acc[q * 4 + 3] = bv.w + p0.w + p1.w + p2.w + p3.w;
    }
#pragma unroll
    for (int j = 0; j < 14; ++j) {
        float xj = (j < 6) ? xv[j] : nz[j - 6];
        float4 wa = *(const float4*)&W_in[j * HID + nc];
        float4 wb = *(const float4*)&W_in[j * HID + nc + 4];
        acc[0] += xj * wa.x; acc[1] += xj * wa.y;
        acc[2] += xj * wa.z; acc[3] += xj * wa.w;
        acc[4] += xj * wb.x; acc[5] += xj * wb.y;
        acc[6] += xj * wb.z; acc[7] += xj * wb.w;
    }
    u16x8 hv, lv;
#pragma unroll
    for (int j2 = 0; j2 < 8; ++j2) {
        float g = gelu_f(acc[j2]);
        u16 hi = f2bf(g);
        hv[j2] = hi;
        lv[j2] = f2bf(g - bf2f(hi));
    }
    size_t o = fragoff(r, nc);
    *(u16x8*)&Yh[o] = hv;
    *(u16x8*)&Yl[o] = lv;
}

// ---------------------------------------------------------------------------
// G1..G4: split-bf16 3-pass MFMA, counted-vmcnt pipeline, frag staging.
// NEW tile: block 32 rows x 128 cols, 4 waves (256 thr), wave tile 32x32
// (2x2 fragments) -> 8 ds_read_b128 feed 12 MFMAs per step (ratio 0.67 vs
// 1.0 before; inner loop was LDS-read-bound). Grid (128,4) = 512 blocks =
// 2 blocks/CU (round-4-proven occupancy). BK=32, 16 steps, 3 slots, 2-deep
// prefetch, vmcnt(5) in-loop (5 loads/wave/stage), one s_barrier per step.
// Publication proof: each wave waits vmcnt for ITS OWN stage(c) loads BEFORE
// the barrier; barrier then publishes all waves' stage(c) to all readers.
// Restage(c+2) overwrites slot (c-1)%3: all its readers completed their
// ds_reads before passing the top-of-step-c barrier.
// LDS slot layout: [20][512] u16 = A(idx 0..3: pl*2+g) | B(idx 4+pl*8+g).
// ---------------------------------------------------------------------------
__global__ __launch_bounds__(256) void k_gemm_f(
        const u16* __restrict__ Ah, const u16* __restrict__ Al,
        const u16* __restrict__ Wh, const u16* __restrict__ Wl,
        const float* __restrict__ bias,
        u16* __restrict__ Yh, u16* __restrict__ Yl) {
    __shared__ __align__(16) u16 lds[3][20][512];   // 60 KB
    int tid = threadIdx.x, lane = tid & 63, w = tid >> 6;  // w: 0..3
    int m0 = blockIdx.x * 32, n0 = blockIdx.y * 128;

    // staging ownership: wave w -> A load (pl=w>>1, g=w&1) + B grps {2w,2w+1} x 2 planes
    int apl = w >> 1, ag = w & 1;
    const u16* aplane = apl ? Al : Ah;
    const u16* srcA = aplane + (size_t)((blockIdx.x * 2 + ag) * 16) * 512 + lane * 8;
    const u16* srcB0 = Wh + (size_t)((blockIdx.y * 8 + 2 * w) * 16) * 512 + lane * 8;
    const u16* srcB1 = Wh + (size_t)((blockIdx.y * 8 + 2 * w + 1) * 16) * 512 + lane * 8;
    const u16* srcB2 = Wl + (size_t)((blockIdx.y * 8 + 2 * w) * 16) * 512 + lane * 8;
    const u16* srcB3 = Wl + (size_t)((blockIdx.y * 8 + 2 * w + 1) * 16) * 512 + lane * 8;

    auto stage = [&](int c, int sl) {
        __builtin_amdgcn_global_load_lds(
            (const __attribute__((address_space(1))) void*)(srcA + c * 512),
            (__attribute__((address_space(3))) void*)&lds[sl][apl * 2 + ag][0], 16, 0, 0);
        __builtin_amdgcn_global_load_lds(
            (const __attribute__((address_space(1))) void*)(srcB0 + c * 512),
            (__attribute__((address_space(3))) void*)&lds[sl][4 + 2 * w][0], 16, 0, 0);
        __builtin_amdgcn_global_load_lds(
            (const __attribute__((address_space(1))) void*)(srcB1 + c * 512),
            (__attribute__((address_space(3))) void*)&lds[sl][4 + 2 * w + 1][0], 16, 0, 0);
        __builtin_amdgcn_global_load_lds(
            (const __attribute__((address_space(1))) void*)(srcB2 + c * 512),
            (__attribute__((address_space(3))) void*)&lds[sl][12 + 2 * w][0], 16, 0, 0);
        __builtin_amdgcn_global_load_lds(
            (const __attribute__((address_space(1))) void*)(srcB3 + c * 512),
            (__attribute__((address_space(3))) void*)&lds[sl][12 + 2 * w + 1][0], 16, 0, 0);
    };

    f32x4 zero = {0.f, 0.f, 0.f, 0.f};
    f32x4 acc[2][2] = {{zero, zero}, {zero, zero}};

    stage(0, 0);
    stage(1, 1);
#pragma unroll
    for (int c = 0; c < 16; ++c) {
        int sl = c % 3;
        if (c < 15) { asm volatile("s_waitcnt vmcnt(5)" ::: "memory"); }
        else        { asm volatile("s_waitcnt vmcnt(0)" ::: "memory"); }
        __builtin_amdgcn_s_barrier();
        __builtin_amdgcn_sched_barrier(0);

        bf16x8 ah[2], al[2], bh[2], bl[2];
#pragma unroll
        for (int i = 0; i < 2; ++i) {
            ah[i] = *(const bf16x8*)&lds[sl][i][lane * 8];
            al[i] = *(const bf16x8*)&lds[sl][2 + i][lane * 8];
        }
#pragma unroll
        for (int j = 0; j < 2; ++j) {
            bh[j] = *(const bf16x8*)&lds[sl][4 + 2 * w + j][lane * 8];
            bl[j] = *(const bf16x8*)&lds[sl][12 + 2 * w + j][lane * 8];
        }
        __builtin_amdgcn_s_setprio(1);
#pragma unroll
        for (int i = 0; i < 2; ++i)
#pragma unroll
            for (int j = 0; j < 2; ++j) {
                acc[i][j] = __builtin_amdgcn_mfma_f32_16x16x32_bf16(ah[i], bh[j], acc[i][j], 0, 0, 0);
                acc[i][j] = __builtin_amdgcn_mfma_f32_16x16x32_bf16(ah[i], bl[j], acc[i][j], 0, 0, 0);
                acc[i][j] = __builtin_amdgcn_mfma_f32_16x16x32_bf16(al[i], bh[j], acc[i][j], 0, 0, 0);
            }
        __builtin_amdgcn_s_setprio(0);
        __builtin_amdgcn_sched_barrier(0);
        if (c < 14) stage(c + 2, (c + 2) % 3);
    }

#pragma unroll
    for (int i = 0; i < 2; ++i) {
        int row0 = m0 + i * 16 + (lane >> 4) * 4;
#pragma unroll
        for (int j = 0; j < 2; ++j) {
            int col = n0 + w * 32 + j * 16 + (lane & 15);
            float bia = bias[col];
#pragma unroll
            for (int r2 = 0; r2 < 4; ++r2) {
                float g = gelu_f(acc[i][j][r2] + bia);
                u16 hi = f2bf(g);
                size_t o = fragoff(row0 + r2, col);
                Yh[o] = hi;
                Yl[o] = f2bf(g - bf2f(hi));
            }
        }
    }
}

// ---------------------------------------------------------------------------
// out_fk: output layer for BOTH steps + DDIM + tanh + FK + select -> d_out.
// One wave per batch element; lanes 0/1 run FK for step 0/1 in parallel.
// ---------------------------------------------------------------------------
__device__ void mat4mul(float C[4][4], const float A[4][4], const float Bm[4][4]) {
#pragma unroll
    for (int i = 0; i < 4; ++i)
#pragma unroll
        for (int j = 0; j < 4; ++j) {
            float s = A[i][0] * Bm[0][j];
            s += A[i][1] * Bm[1][j];
            s += A[i][2] * Bm[2][j];
            s += A[i][3] * Bm[3][j];
            C[i][j] = s;
        }
}

__global__ __launch_bounds__(256) void k_out_fk(
        const u16* __restrict__ Yh, const u16* __restrict__ Yl,
        const float* __restrict__ W_out, const float* __restrict__ b_out,
        const float* __restrict__ noise, const float* __restrict__ x_pre,
        float* __restrict__ out, float c1, float c2, float c3) {
    int b = blockIdx.x * 4 + (threadIdx.x >> 6);
    int lane = threadIdx.x & 63;

    float acc0[8] = {0, 0, 0, 0, 0, 0, 0, 0};
    float acc1[8] = {0, 0, 0, 0, 0, 0, 0, 0};
#pragma unroll
    for (int it = 0; it < 8; ++it) {
        int k = lane + it * 64;
        size_t o0 = fragoff(b, k);
        size_t o1 = fragoff(BATCH + b, k);
        float ya = bf2f(Yh[o0]) + bf2f(Yl[o0]);
        float yb = bf2f(Yh[o1]) + bf2f(Yl[o1]);
        float4 w0 = ((const float4*)&W_out[k * NACT])[0];
        float4 w1 = ((const float4*)&W_out[k * NACT])[1];
        acc0[0] += ya * w0.x; acc0[1] += ya * w0.y; acc0[2] += ya * w0.z; acc0[3] += ya * w0.w;
        acc0[4] += ya * w1.x; acc0[5] += ya * w1.y; acc0[6] += ya * w1.z; acc0[7] += ya * w1.w;
        acc1[0] += yb * w0.x; acc1[1] += yb * w0.y; acc1[2] += yb * w0.z; acc1[3] += yb * w0.w;
        acc1[4] += yb * w1.x; acc1[5] += yb * w1.y; acc1[6] += yb * w1.z; acc1[7] += yb * w1.w;
    }
#pragma unroll
    for (int n = 0; n < 8; ++n) {
#pragma unroll
        for (int off = 32; off > 0; off >>= 1) {
            acc0[n] += __shfl_xor(acc0[n], off, 64);
            acc1[n] += __shfl_xor(acc1[n], off, 64);
        }
    }

    float jq[8] = {0, 0, 0, 0, 0, 0, 0, 0};
    float err = 0.f;
    if (lane < 2) {
        int s = lane;
        const float* accp = (s == 0) ? acc0 : acc1;
        const float HIf[8] = {
            (float)(35.0 * M_PI / 180.0), (float)(-60.0 * M_PI / 180.0), 3.94f,
            (float)(155.0 * M_PI / 180.0), (float)(-55.0 * M_PI / 180.0),
            (float)M_PI, (float)(5.0 * M_PI / 180.0), 3.71f};
        const float LOf[8] = {
            (float)(-35.0 * M_PI / 180.0), (float)(-155.0 * M_PI / 180.0), 2.59f,
            (float)(60.0 * M_PI / 180.0), (float)(-125.0 * M_PI / 180.0),
            (float)(-M_PI), (float)(-90.0 * M_PI / 180.0), 2.5f};
        const float* nzp = &noise[(s * BATCH + b) * NACT];
#pragma unroll
        for (int n = 0; n < 8; ++n) {
            float o = accp[n] + b_out[n];
            float z = c1 * nzp[n] + c2 * o + c3 * nzp[n];
            float jn = (tanhf(z * 0.1f) + 1.0f) * 0.5f;
            jq[n] = jn * (HIf[n] - LOf[n]) + LOf[n];
        }
        const float a_[8]  = {0.0f, 0.16f, 0.07f, 0.0f, 0.1334f, 0.0f, 0.15f, 0.3625f};
        const float ca_[8] = {1.f, 0.f, 0.f, 0.f, 0.f, 0.f, 0.f, 0.f};
        const float sa_[8] = {0.f, -1.f, -1.f, 1.f, -1.f, -1.f, 1.f, -1.f};
        float d_[8] = {0.0f, 0.0f, jq[2], 0.0f, -0.1316f, 1.0105f, 0.52f, jq[7]};
        float th[8] = {jq[0], jq[1], 0.0f, jq[3], jq[4], jq[5], jq[6], 0.0f};
        float T[4][4], M[4][4], Tn[4][4];
#pragma unroll
        for (int j = 0; j < 8; ++j) {
            float ct = cosf(th[j]);
            float st = sinf(th[j]);
            M[0][0] = ct;          M[0][1] = -st;         M[0][2] = 0.0f;    M[0][3] = a_[j];
            M[1][0] = st * ca_[j]; M[1][1] = ct * ca_[j]; M[1][2] = -sa_[j]; M[1][3] = -sa_[j] * d_[j];
            M[2][0] = st * sa_[j]; M[2][1] = ct * sa_[j]; M[2][2] = ca_[j];  M[2][3] = ca_[j] * d_[j];
            M[3][0] = 0.0f;        M[3][1] = 0.0f;        M[3][2] = 0.0f;    M[3][3] = 1.0f;
            if (j == 0) {
#pragma unroll
                for (int i = 0; i < 4; ++i)
#pragma unroll
                    for (int cc = 0; cc < 4; ++cc) T[i][cc] = M[i][cc];
            } else {
                mat4mul(Tn, T, M);
#pragma unroll
                for (int i = 0; i < 4; ++i)
#pragma unroll
                    for (int cc = 0; cc < 4; ++cc) T[i][cc] = Tn[i][cc];
            }
        }
        float e1x = T[0][2] * 3.75f;
        float e1y = T[1][2] * 3.75f;
        float e1z = T[2][2] * 3.75f;
        float p0 = T[0][3];
        float p1 = T[1][3];
        float p2 = T[2][3] + 1.702f;
        float p3 = e1x + T[0][3];
        float p4 = e1y + T[1][3];
        float p5 = e1z + T[2][3] + 1.702f;
        const float* xp = &x_pre[b * 6];
        float dx0 = 100.0f * p0 - xp[0];
        float dx1 = 100.0f * p1 - xp[1];
        float dx2 = 100.0f * p2 - xp[2];
        float dx3 = 100.0f * p3 - xp[3];
        float dx4 = 100.0f * p4 - xp[4];
        float dx5 = 100.0f * p5 - xp[5];
        err = sqrtf(dx0 * dx0 + dx1 * dx1 + dx2 * dx2) +
              sqrtf(dx3 * dx3 + dx4 * dx4 + dx5 * dx5);
    }
    float e0 = __shfl(err, 0, 64);
    float e1 = __shfl(err, 1, 64);
    int sel = (e1 < e0) ? 1 : 0;   // first index wins ties
    float jsel[8];
#pragma unroll
    for (int n = 0; n < 8; ++n) jsel[n] = __shfl(jq[n], sel, 64);
    if (lane == 0) {
#pragma unroll
        for (int n = 0; n < 8; ++n) out[b * NACT + n] = jsel[n];
    }
}

// ===========================================================================
extern "C" void kernel_launch(void* const* d_in, const int* in_sizes, int n_in,
                              void* d_out, int out_size, void* d_ws, size_t ws_size,
                              hipStream_t stream) {
    const float* x_pre = (const float*)d_in[0];
    const float* noise = (const float*)d_in[1];
    const float* W_in  = (const float*)d_in[2];
    const float* b_in  = (const float*)d_in[3];
    const float* W1    = (const float*)d_in[4];
    const float* b1    = (const float*)d_in[5];
    const float* W2    = (const float*)d_in[6];
    const float* b2    = (const float*)d_in[7];
    const float* W3    = (const float*)d_in[8];
    const float* b3    = (const float*)d_in[9];
    const float* W4    = (const float*)d_in[10];
    const float* b4    = (const float*)d_in[11];
    const float* W_out = (const float*)d_in[12];
    const float* b_out = (const float*)d_in[13];

    // DDIM last-step coefficients (only the last loop iteration matters:
    // z is overwritten every iteration in the reference, nz never updated).
    double ab_c = exp(-0.1 * 50.0 / 1000.0 - 0.5 * (10.0 - 0.1) * 2500.0 / 1.0e6);
    float c1 = (float)sqrt(1.0 / ab_c);
    float c2 = (float)(-sqrt((1.0 - ab_c) / ab_c));
    float c3 = (float)sqrt(1.0 - ab_c);

    char* base = (char*)d_ws;
    u16* Ah = (u16*)base;                        // 4 activation planes, 4 MB each
    u16* Al = Ah + 2097152;
    u16* Bh = Al + 2097152;
    u16* Bl = Bh + 2097152;
    u16* wt = (u16*)(base + 16777216);           // 4 layers x (hi,lo) frag planes
    float* partials = (float*)(base + 16777216 + 4194304); // 4x512

    k_prep<<<dim3(16, 16, 5), 256, 0, stream>>>(W1, W2, W3, W4, W_in, wt, partials);
    k_layer_in<<<ROWS * 64 / 256, 256, 0, stream>>>(x_pre, noise, W_in, b_in,
                                                    partials, Ah, Al);
    dim3 g(ROWS / 32, HID / 128);
    k_gemm_f<<<g, 256, 0, stream>>>(Ah, Al, wt + 0 * 524288, wt + 0 * 524288 + 262144, b1, Bh, Bl);
    k_gemm_f<<<g, 256, 0, stream>>>(Bh, Bl, wt + 1 * 524288, wt + 1 * 524288 + 262144, b2, Ah, Al);
    k_gemm_f<<<g, 256, 0, stream>>>(Ah, Al, wt + 2 * 524288, wt + 2 * 524288 + 262144, b3, Bh, Bl);
    k_gemm_f<<<g, 256, 0, stream>>>(Bh, Bl, wt + 3 * 524288, wt + 3 * 524288 + 262144, b4, Ah, Al);
    k_out_fk<<<BATCH / 4, 256, 0, stream>>>(Ah, Al, W_out, b_out, noise, x_pre,
                                            (float*)d_out, c1, c2, c3);
}

// Round 12
// 90.620 us; speedup vs baseline: 1.0361x; 1.0361x over previous
//
#include <hip/hip_runtime.h>
#include <math.h>

typedef __bf16 bf16x8 __attribute__((ext_vector_type(8)));
typedef float f32x4 __attribute__((ext_vector_type(4)));
typedef unsigned short u16;
typedef unsigned short u16x8 __attribute__((ext_vector_type(8)));
typedef unsigned int u32;

constexpr int BATCH = 2048;
constexpr int ROWS  = 4096;   // 2 steps x 2048
constexpr int HID   = 512;
constexpr int NACT  = 8;

__device__ __forceinline__ float gelu_f(float x) {
    return 0.5f * x * (1.0f + erff(x * 0.70710678118654752f));
}
__device__ __forceinline__ u16 f2bf(float f) {
    u32 u = __float_as_uint(f);
    return (u16)((u + 0x7FFFu + ((u >> 16) & 1u)) >> 16);
}
__device__ __forceinline__ float bf2f(u16 h) {
    return __uint_as_float(((u32)h) << 16);
}

// Fragment-chunk layout for every bf16 plane:
//   plane[(r>>4)*16 + (k>>5)][512], idx = (((k&31)>>3)*16 + (r&15))*8 + (k&7)
// A 16-row x 32-k tile is one contiguous 1KB block in exact MFMA-fragment
// lane order -> staging loads are single contiguous 1KB bursts.
__device__ __forceinline__ size_t fragoff(int r, int k) {
    return (size_t)(((r >> 4) * 16 + (k >> 5)) * 512
                    + (((k & 31) >> 3) * 16 + (r & 15)) * 8 + (k & 7));
}

// ---------------------------------------------------------------------------
// K_prep: z<4 -> transpose + hi/lo-split weight layer z into wt (frag layout)
//         z==4 (x<4,y==0) -> partials[x] = temb-slice @ W_in slice (no
//         cross-block reduction: summed by consumers; deterministic).
// ---------------------------------------------------------------------------
__global__ __launch_bounds__(256) void k_prep(
        const float* __restrict__ W1, const float* __restrict__ W2,
        const float* __restrict__ W3, const float* __restrict__ W4,
        const float* __restrict__ W_in,
        u16* __restrict__ wt, float* __restrict__ partials) {
    int z = blockIdx.z;
    if (z == 4) {
        if (blockIdx.x >= 4 || blockIdx.y != 0) return;
        __shared__ float temb[128];
        int x = blockIdx.x, t = threadIdx.x;
        if (t < 128) {
            int k = x * 128 + t;
            int p = k >> 1;
            float div = expf((float)(2 * p) * (-9.210340371976184f / 512.0f));
            temb[t] = (k & 1) ? cosf(49.0f * div) : sinf(49.0f * div);
        }
        __syncthreads();
#pragma unroll
        for (int half = 0; half < 2; ++half) {
            int col = half * 256 + t;
            float acc = 0.f;
            for (int kk = 0; kk < 128; ++kk)
                acc += temb[kk] * W_in[(size_t)(14 + x * 128 + kk) * HID + col];
            partials[x * HID + col] = acc;
        }
        return;
    }
    __shared__ float tile[32][33];
    const float* Ws[4] = {W1, W2, W3, W4};
    const float* W = Ws[z];
    u16* wh = wt + (size_t)z * 524288;
    u16* wl = wh + 262144;
    int kt = blockIdx.x * 32, nt = blockIdx.y * 32, t = threadIdx.x;
    int c = t & 31, r = t >> 5;
#pragma unroll
    for (int p = 0; p < 4; ++p)
        tile[r + p * 8][c] = W[(size_t)(kt + r + p * 8) * HID + nt + c];
    __syncthreads();
#pragma unroll
    for (int p = 0; p < 4; ++p) {
        int nl = r + p * 8, kl = c;
        float v = tile[kl][nl];
        u16 h = f2bf(v);
        u16 l2 = f2bf(v - bf2f(h));
        size_t o = fragoff(nt + nl, kt + kl);
        wh[o] = h;
        wl[o] = l2;
    }
}

// ---------------------------------------------------------------------------
// K_layer_in: input layer, each element computed once. One wave per row;
// lane o computes col-octet o: float4 weight loads, u16x8 frag stores.
// ---------------------------------------------------------------------------
__global__ __launch_bounds__(256) void k_layer_in(
        const float* __restrict__ x_pre, const float* __restrict__ noise,
        const float* __restrict__ W_in, const float* __restrict__ b_in,
        const float* __restrict__ partials,
        u16* __restrict__ Yh, u16* __restrict__ Yl) {
    int id = blockIdx.x * 256 + threadIdx.x;
    int r = id >> 6, oct = id & 63;
    int s = r >> 11, bidx = r & 2047;
    float xv[6], nz[8];
#pragma unroll
    for (int j = 0; j < 6; ++j) xv[j] = x_pre[bidx * 6 + j];
#pragma unroll
    for (int j = 0; j < 8; ++j) nz[j] = noise[(s * BATCH + bidx) * NACT + j];
    int nc = oct * 8;
    float acc[8];
#pragma unroll
    for (int q = 0; q < 2; ++q) {
        float4 bv = *(const float4*)&b_in[nc + q * 4];
        float4 p0 = *(const float4*)&partials[nc + q * 4];
        float4 p1 = *(const float4*)&partials[512 + nc + q * 4];
        float4 p2 = *(const float4*)&partials[1024 + nc + q * 4];
        float4 p3 = *(const float4*)&partials[1536 + nc + q * 4];
        acc[q * 4 + 0] = bv.x + p0.x + p1.x + p2.x + p3.x;
        acc[q * 4 + 1] = bv.y + p0.y + p1.y + p2.y + p3.y;
        acc[q * 4 + 2] = bv.z + p0.z + p1.z + p2.z + p3.z;
        acc[q * 4 + 3] = bv.w + p0.w + p1.w + p2.w + p3.w;
    }
#pragma unroll
    for (int j = 0; j < 14; ++j) {
        float xj = (j < 6) ? xv[j] : nz[j - 6];
        float4 wa = *(const float4*)&W_in[j * HID + nc];
        float4 wb = *(const float4*)&W_in[j * HID + nc + 4];
        acc[0] += xj * wa.x; acc[1] += xj * wa.y;
        acc[2] += xj * wa.z; acc[3] += xj * wa.w;
        acc[4] += xj * wb.x; acc[5] += xj * wb.y;
        acc[6] += xj * wb.z; acc[7] += xj * wb.w;
    }
    u16x8 hv, lv;
#pragma unroll
    for (int j2 = 0; j2 < 8; ++j2) {
        float g = gelu_f(acc[j2]);
        u16 hi = f2bf(g);
        hv[j2] = hi;
        lv[j2] = f2bf(g - bf2f(hi));
    }
    size_t o = fragoff(r, nc);
    *(u16x8*)&Yh[o] = hv;
    *(u16x8*)&Yl[o] = lv;
}

// ---------------------------------------------------------------------------
// G1..G4: split-bf16 3-pass MFMA, K-SPLIT-2 tile:
// Block 64x64, 512 thr (8 waves), grid (64,8)=512 blocks -> 2 blocks/CU,
// 16 waves/CU (round-10 occupancy). Wave w: quadrant q=w&3 (qr=q>>1 rows,
// qc=q&1 cols, 32x32 tile), K-half kh=w>>2 (k-chunks kh*8..kh*8+7).
// Per step: 8 ds_read_b128 feed 12 MFMAs (ratio 0.67 vs round-10's 1.0) ->
// per-CU LDS reads/layer 1536 -> 1024. Partner accs summed via LDS at end.
// Staging: 32x 1KB chunks/step (16/half), 4 per wave, double-buffered
// (64KB LDS), vmcnt(4) in-loop. Publication: each wave waits for ITS OWN
// stage(s) loads before the barrier; barrier publishes to all readers.
// ---------------------------------------------------------------------------
__global__ __launch_bounds__(512) void k_gemm_f(
        const u16* __restrict__ Ah, const u16* __restrict__ Al,
        const u16* __restrict__ Wh, const u16* __restrict__ Wl,
        const float* __restrict__ bias,
        u16* __restrict__ Yh, u16* __restrict__ Yl) {
    __shared__ __align__(16) u16 lds[2][2][16][512];   // [slot][kh][chunk] 64 KB
    int tid = threadIdx.x, lane = tid & 63, w = tid >> 6;
    int q = w & 3, kh = w >> 2;
    int qr = q >> 1, qc = q & 1;
    int m0 = blockIdx.x * 64, n0 = blockIdx.y * 64;

    // staging: wave stages A chunks {2q,2q+1} and B chunks {2q,2q+1} of its half
    // chunk id a: pl = a>>2, g = a&3 ; source chunk index = (grp*16 + kc)
    int a0 = 2 * q, a1 = 2 * q + 1;
    int apl0 = a0 >> 2, ag0 = a0 & 3, apl1 = a1 >> 2, ag1 = a1 & 3;
    const u16* srcA0 = (apl0 ? Al : Ah) + (size_t)((blockIdx.x * 4 + ag0) * 16 + kh * 8) * 512 + lane * 8;
    const u16* srcA1 = (apl1 ? Al : Ah) + (size_t)((blockIdx.x * 4 + ag1) * 16 + kh * 8) * 512 + lane * 8;
    const u16* srcB0 = (apl0 ? Wl : Wh) + (size_t)((blockIdx.y * 4 + ag0) * 16 + kh * 8) * 512 + lane * 8;
    const u16* srcB1 = (apl1 ? Wl : Wh) + (size_t)((blockIdx.y * 4 + ag1) * 16 + kh * 8) * 512 + lane * 8;

    auto stage = [&](int s, int sl) {
        __builtin_amdgcn_global_load_lds(
            (const __attribute__((address_space(1))) void*)(srcA0 + s * 512),
            (__attribute__((address_space(3))) void*)&lds[sl][kh][a0][0], 16, 0, 0);
        __builtin_amdgcn_global_load_lds(
            (const __attribute__((address_space(1))) void*)(srcA1 + s * 512),
            (__attribute__((address_space(3))) void*)&lds[sl][kh][a1][0], 16, 0, 0);
        __builtin_amdgcn_global_load_lds(
            (const __attribute__((address_space(1))) void*)(srcB0 + s * 512),
            (__attribute__((address_space(3))) void*)&lds[sl][kh][8 + a0][0], 16, 0, 0);
        __builtin_amdgcn_global_load_lds(
            (const __attribute__((address_space(1))) void*)(srcB1 + s * 512),
            (__attribute__((address_space(3))) void*)&lds[sl][kh][8 + a1][0], 16, 0, 0);
    };

    f32x4 zero = {0.f, 0.f, 0.f, 0.f};
    f32x4 acc[2][2] = {{zero, zero}, {zero, zero}};

    stage(0, 0);
#pragma unroll
    for (int s = 0; s < 8; ++s) {
        int sl = s & 1;
        if (s < 7) {
            stage(s + 1, sl ^ 1);
            asm volatile("s_waitcnt vmcnt(4)" ::: "memory");
        } else {
            asm volatile("s_waitcnt vmcnt(0)" ::: "memory");
        }
        __builtin_amdgcn_s_barrier();
        __builtin_amdgcn_sched_barrier(0);

        bf16x8 ah[2], al[2], bh[2], bl[2];
#pragma unroll
        for (int i = 0; i < 2; ++i) {
            ah[i] = *(const bf16x8*)&lds[sl][kh][qr * 2 + i][lane * 8];       // A pl0
            al[i] = *(const bf16x8*)&lds[sl][kh][4 + qr * 2 + i][lane * 8];   // A pl1
        }
#pragma unroll
        for (int j = 0; j < 2; ++j) {
            bh[j] = *(const bf16x8*)&lds[sl][kh][8 + qc * 2 + j][lane * 8];   // B pl0
            bl[j] = *(const bf16x8*)&lds[sl][kh][12 + qc * 2 + j][lane * 8];  // B pl1
        }
        __builtin_amdgcn_s_setprio(1);
#pragma unroll
        for (int i = 0; i < 2; ++i)
#pragma unroll
            for (int j = 0; j < 2; ++j) {
                acc[i][j] = __builtin_amdgcn_mfma_f32_16x16x32_bf16(ah[i], bh[j], acc[i][j], 0, 0, 0);
                acc[i][j] = __builtin_amdgcn_mfma_f32_16x16x32_bf16(ah[i], bl[j], acc[i][j], 0, 0, 0);
                acc[i][j] = __builtin_amdgcn_mfma_f32_16x16x32_bf16(al[i], bh[j], acc[i][j], 0, 0, 0);
            }
        __builtin_amdgcn_s_setprio(0);
        __builtin_amdgcn_sched_barrier(0);
    }

    // ---- K-half reduction: kh=1 waves publish acc, kh=0 waves sum ----
    __syncthreads();   // all waves done reading slot LDS -> safe to reuse
    float* red = (float*)&lds[0][0][0][0];   // 16 KB
    if (kh == 1) {
#pragma unroll
        for (int f = 0; f < 4; ++f)
            *(f32x4*)&red[(q * 64 + lane) * 16 + f * 4] = acc[f >> 1][f & 1];
    }
    __syncthreads();
    if (kh == 0) {
#pragma unroll
        for (int f = 0; f < 4; ++f) {
            f32x4 p = *(const f32x4*)&red[(q * 64 + lane) * 16 + f * 4];
            acc[f >> 1][f & 1] += p;
        }
#pragma unroll
        for (int i = 0; i < 2; ++i) {
            int row0 = m0 + qr * 32 + i * 16 + (lane >> 4) * 4;
#pragma unroll
            for (int j = 0; j < 2; ++j) {
                int col = n0 + qc * 32 + j * 16 + (lane & 15);
                float bia = bias[col];
#pragma unroll
                for (int r2 = 0; r2 < 4; ++r2) {
                    float g = gelu_f(acc[i][j][r2] + bia);
                    u16 hi = f2bf(g);
                    size_t o = fragoff(row0 + r2, col);
                    Yh[o] = hi;
                    Yl[o] = f2bf(g - bf2f(hi));
                }
            }
        }
    }
}

// ---------------------------------------------------------------------------
// out_fk: output layer for BOTH steps + DDIM + tanh + FK + select -> d_out.
// One wave per batch element; lanes 0/1 run FK for step 0/1 in parallel.
// ---------------------------------------------------------------------------
__device__ void mat4mul(float C[4][4], const float A[4][4], const float Bm[4][4]) {
#pragma unroll
    for (int i = 0; i < 4; ++i)
#pragma unroll
        for (int j = 0; j < 4; ++j) {
            float s = A[i][0] * Bm[0][j];
            s += A[i][1] * Bm[1][j];
            s += A[i][2] * Bm[2][j];
            s += A[i][3] * Bm[3][j];
            C[i][j] = s;
        }
}

__global__ __launch_bounds__(256) void k_out_fk(
        const u16* __restrict__ Yh, const u16* __restrict__ Yl,
        const float* __restrict__ W_out, const float* __restrict__ b_out,
        const float* __restrict__ noise, const float* __restrict__ x_pre,
        float* __restrict__ out, float c1, float c2, float c3) {
    int b = blockIdx.x * 4 + (threadIdx.x >> 6);
    int lane = threadIdx.x & 63;

    float acc0[8] = {0, 0, 0, 0, 0, 0, 0, 0};
    float acc1[8] = {0, 0, 0, 0, 0, 0, 0, 0};
#pragma unroll
    for (int it = 0; it < 8; ++it) {
        int k = lane + it * 64;
        size_t o0 = fragoff(b, k);
        size_t o1 = fragoff(BATCH + b, k);
        float ya = bf2f(Yh[o0]) + bf2f(Yl[o0]);
        float yb = bf2f(Yh[o1]) + bf2f(Yl[o1]);
        float4 w0 = ((const float4*)&W_out[k * NACT])[0];
        float4 w1 = ((const float4*)&W_out[k * NACT])[1];
        acc0[0] += ya * w0.x; acc0[1] += ya * w0.y; acc0[2] += ya * w0.z; acc0[3] += ya * w0.w;
        acc0[4] += ya * w1.x; acc0[5] += ya * w1.y; acc0[6] += ya * w1.z; acc0[7] += ya * w1.w;
        acc1[0] += yb * w0.x; acc1[1] += yb * w0.y; acc1[2] += yb * w0.z; acc1[3] += yb * w0.w;
        acc1[4] += yb * w1.x; acc1[5] += yb * w1.y; acc1[6] += yb * w1.z; acc1[7] += yb * w1.w;
    }
#pragma unroll
    for (int n = 0; n < 8; ++n) {
#pragma unroll
        for (int off = 32; off > 0; off >>= 1) {
            acc0[n] += __shfl_xor(acc0[n], off, 64);
            acc1[n] += __shfl_xor(acc1[n], off, 64);
        }
    }

    float jq[8] = {0, 0, 0, 0, 0, 0, 0, 0};
    float err = 0.f;
    if (lane < 2) {
        int s = lane;
        const float* accp = (s == 0) ? acc0 : acc1;
        const float HIf[8] = {
            (float)(35.0 * M_PI / 180.0), (float)(-60.0 * M_PI / 180.0), 3.94f,
            (float)(155.0 * M_PI / 180.0), (float)(-55.0 * M_PI / 180.0),
            (float)M_PI, (float)(5.0 * M_PI / 180.0), 3.71f};
        const float LOf[8] = {
            (float)(-35.0 * M_PI / 180.0), (float)(-155.0 * M_PI / 180.0), 2.59f,
            (float)(60.0 * M_PI / 180.0), (float)(-125.0 * M_PI / 180.0),
            (float)(-M_PI), (float)(-90.0 * M_PI / 180.0), 2.5f};
        const float* nzp = &noise[(s * BATCH + b) * NACT];
#pragma unroll
        for (int n = 0; n < 8; ++n) {
            float o = accp[n] + b_out[n];
            float z = c1 * nzp[n] + c2 * o + c3 * nzp[n];
            float jn = (tanhf(z * 0.1f) + 1.0f) * 0.5f;
            jq[n] = jn * (HIf[n] - LOf[n]) + LOf[n];
        }
        const float a_[8]  = {0.0f, 0.16f, 0.07f, 0.0f, 0.1334f, 0.0f, 0.15f, 0.3625f};
        const float ca_[8] = {1.f, 0.f, 0.f, 0.f, 0.f, 0.f, 0.f, 0.f};
        const float sa_[8] = {0.f, -1.f, -1.f, 1.f, -1.f, -1.f, 1.f, -1.f};
        float d_[8] = {0.0f, 0.0f, jq[2], 0.0f, -0.1316f, 1.0105f, 0.52f, jq[7]};
        float th[8] = {jq[0], jq[1], 0.0f, jq[3], jq[4], jq[5], jq[6], 0.0f};
        float T[4][4], M[4][4], Tn[4][4];
#pragma unroll
        for (int j = 0; j < 8; ++j) {
            float ct = cosf(th[j]);
            float st = sinf(th[j]);
            M[0][0] = ct;          M[0][1] = -st;         M[0][2] = 0.0f;    M[0][3] = a_[j];
            M[1][0] = st * ca_[j]; M[1][1] = ct * ca_[j]; M[1][2] = -sa_[j]; M[1][3] = -sa_[j] * d_[j];
            M[2][0] = st * sa_[j]; M[2][1] = ct * sa_[j]; M[2][2] = ca_[j];  M[2][3] = ca_[j] * d_[j];
            M[3][0] = 0.0f;        M[3][1] = 0.0f;        M[3][2] = 0.0f;    M[3][3] = 1.0f;
            if (j == 0) {
#pragma unroll
                for (int i = 0; i < 4; ++i)
#pragma unroll
                    for (int cc = 0; cc < 4; ++cc) T[i][cc] = M[i][cc];
            } else {
                mat4mul(Tn, T, M);
#pragma unroll
                for (int i = 0; i < 4; ++i)
#pragma unroll
                    for (int cc = 0; cc < 4; ++cc) T[i][cc] = Tn[i][cc];
            }
        }
        float e1x = T[0][2] * 3.75f;
        float e1y = T[1][2] * 3.75f;
        float e1z = T[2][2] * 3.75f;
        float p0 = T[0][3];
        float p1 = T[1][3];
        float p2 = T[2][3] + 1.702f;
        float p3 = e1x + T[0][3];
        float p4 = e1y + T[1][3];
        float p5 = e1z + T[2][3] + 1.702f;
        const float* xp = &x_pre[b * 6];
        float dx0 = 100.0f * p0 - xp[0];
        float dx1 = 100.0f * p1 - xp[1];
        float dx2 = 100.0f * p2 - xp[2];
        float dx3 = 100.0f * p3 - xp[3];
        float dx4 = 100.0f * p4 - xp[4];
        float dx5 = 100.0f * p5 - xp[5];
        err = sqrtf(dx0 * dx0 + dx1 * dx1 + dx2 * dx2) +
              sqrtf(dx3 * dx3 + dx4 * dx4 + dx5 * dx5);
    }
    float e0 = __shfl(err, 0, 64);
    float e1 = __shfl(err, 1, 64);
    int sel = (e1 < e0) ? 1 : 0;   // first index wins ties
    float jsel[8];
#pragma unroll
    for (int n = 0; n < 8; ++n) jsel[n] = __shfl(jq[n], sel, 64);
    if (lane == 0) {
#pragma unroll
        for (int n = 0; n < 8; ++n) out[b * NACT + n] = jsel[n];
    }
}

// ===========================================================================
extern "C" void kernel_launch(void* const* d_in, const int* in_sizes, int n_in,
                              void* d_out, int out_size, void* d_ws, size_t ws_size,
                              hipStream_t stream) {
    const float* x_pre = (const float*)d_in[0];
    const float* noise = (const float*)d_in[1];
    const float* W_in  = (const float*)d_in[2];
    const float* b_in  = (const float*)d_in[3];
    const float* W1    = (const float*)d_in[4];
    const float* b1    = (const float*)d_in[5];
    const float* W2    = (const float*)d_in[6];
    const float* b2    = (const float*)d_in[7];
    const float* W3    = (const float*)d_in[8];
    const float* b3    = (const float*)d_in[9];
    const float* W4    = (const float*)d_in[10];
    const float* b4    = (const float*)d_in[11];
    const float* W_out = (const float*)d_in[12];
    const float* b_out = (const float*)d_in[13];

    // DDIM last-step coefficients (only the last loop iteration matters:
    // z is overwritten every iteration in the reference, nz never updated).
    double ab_c = exp(-0.1 * 50.0 / 1000.0 - 0.5 * (10.0 - 0.1) * 2500.0 / 1.0e6);
    float c1 = (float)sqrt(1.0 / ab_c);
    float c2 = (float)(-sqrt((1.0 - ab_c) / ab_c));
    float c3 = (float)sqrt(1.0 - ab_c);

    char* base = (char*)d_ws;
    u16* Ah = (u16*)base;                        // 4 activation planes, 4 MB each
    u16* Al = Ah + 2097152;
    u16* Bh = Al + 2097152;
    u16* Bl = Bh + 2097152;
    u16* wt = (u16*)(base + 16777216);           // 4 layers x (hi,lo) frag planes
    float* partials = (float*)(base + 16777216 + 4194304); // 4x512

    k_prep<<<dim3(16, 16, 5), 256, 0, stream>>>(W1, W2, W3, W4, W_in, wt, partials);
    k_layer_in<<<ROWS * 64 / 256, 256, 0, stream>>>(x_pre, noise, W_in, b_in,
                                                    partials, Ah, Al);
    dim3 g(ROWS / 64, HID / 64);
    k_gemm_f<<<g, 512, 0, stream>>>(Ah, Al, wt + 0 * 524288, wt + 0 * 524288 + 262144, b1, Bh, Bl);
    k_gemm_f<<<g, 512, 0, stream>>>(Bh, Bl, wt + 1 * 524288, wt + 1 * 524288 + 262144, b2, Ah, Al);
    k_gemm_f<<<g, 512, 0, stream>>>(Ah, Al, wt + 2 * 524288, wt + 2 * 524288 + 262144, b3, Bh, Bl);
    k_gemm_f<<<g, 512, 0, stream>>>(Bh, Bl, wt + 3 * 524288, wt + 3 * 524288 + 262144, b4, Ah, Al);
    k_out_fk<<<BATCH / 4, 256, 0, stream>>>(Ah, Al, W_out, b_out, noise, x_pre,
                                            (float*)d_out, c1, c2, c3);
}